// Round 17
// baseline (261.772 us; speedup 1.0000x reference)
//
#include <hip/hip_runtime.h>
#include <hip/hip_bf16.h>

#define BATCH 2
#define SEQ 2048
#define DM 1024
#define NH 16
#define DKH 64

typedef __attribute__((ext_vector_type(8))) __bf16 bf16x8;
typedef __attribute__((ext_vector_type(4))) float f32x4;
typedef __attribute__((ext_vector_type(2))) float f32x2;
typedef __attribute__((ext_vector_type(8))) unsigned short ushort8;

__device__ __forceinline__ void gload16(const void* g, void* l) {
  __builtin_amdgcn_global_load_lds(
      (const __attribute__((address_space(1))) void*)g,
      (__attribute__((address_space(3))) void*)l, 16, 0, 0);
}

// -- merged prep: x cast | weight casts | RoPE table | flag zero, 1 launch --
__global__ void prep(const float* __restrict__ x,
                     const float* __restrict__ w0, const float* __restrict__ w1,
                     const float* __restrict__ w2, const float* __restrict__ w3,
                     __bf16* __restrict__ xb, __bf16* __restrict__ wb,
                     float* __restrict__ tab, int* __restrict__ flags) {
  const int bid = blockIdx.x, tid = threadIdx.x;
  if (bid < 2048) {                       // x: 4M elems, 512K chunks of 8
    int i = bid * 256 + tid;
    f32x4 a = ((const f32x4*)x)[2 * i], b = ((const f32x4*)x)[2 * i + 1];
    bf16x8 o;
    o[0]=(__bf16)a[0]; o[1]=(__bf16)a[1]; o[2]=(__bf16)a[2]; o[3]=(__bf16)a[3];
    o[4]=(__bf16)b[0]; o[5]=(__bf16)b[1]; o[6]=(__bf16)b[2]; o[7]=(__bf16)b[3];
    ((bf16x8*)xb)[i] = o;
  } else if (bid < 4096) {                // weights: 4 x 1M elems contiguous dst
    int i = (bid - 2048) * 256 + tid;     // [0, 512K)
    int wi = i >> 17;
    const float* src = (wi == 0) ? w0 : (wi == 1) ? w1 : (wi == 2) ? w2 : w3;
    int li = i & 131071;
    f32x4 a = ((const f32x4*)src)[2 * li], b = ((const f32x4*)src)[2 * li + 1];
    bf16x8 o;
    o[0]=(__bf16)a[0]; o[1]=(__bf16)a[1]; o[2]=(__bf16)a[2]; o[3]=(__bf16)a[3];
    o[4]=(__bf16)b[0]; o[5]=(__bf16)b[1]; o[6]=(__bf16)b[2]; o[7]=(__bf16)b[3];
    ((bf16x8*)wb)[i] = o;
  } else if (bid < 4352) {                // RoPE table: 65536 (s,i) entries
    int idx = (bid - 4096) * 256 + tid;
    int s = idx >> 5, ii = idx & 31;
    float theta = exp2f((float)ii * -0.41524101186092029f);  // 10000^(-i/32)
    float sn, c;
    sincosf((float)s * theta, &sn, &c);
    tab[2 * idx] = c;
    tab[2 * idx + 1] = sn;
  } else {                                // zero split-K fixup flags
    flags[tid] = 0;
  }
}

#define QSCALE 0.1803368801111137f   // 0.125 * log2(e)

// ---------------- GEMM: C[m][n] = sum_k A[m][k] * B[n][k] -----------------
// m97 structure: 128xBN tile, BK=64, single-buffered 32KB LDS, 3 blocks/CU.
// XCD-aware block swizzle (grid linear count divisible by 8; gridDim.x==32).
// EPI 0 (BN=128): QKV projection, N=3072. Q (RoPE*QSCALE), K (RoPE) ->
//        [BH][S][64]; V -> transposed + KEY-PERMUTED [BH][64][S].
// EPI 1 (BN=64): fp32 row-major M x N.
template<int EPI, int BN>
__launch_bounds__(256, 3)
__global__ void gemm_bt(const __bf16* __restrict__ A, const __bf16* __restrict__ B,
                        void* __restrict__ Cout, int M, int N, int K,
                        const float* __restrict__ tab) {
  __shared__ __bf16 As[128 * 64];
  __shared__ __bf16 Bs[BN * 64];
  const int tid = threadIdx.x;
  const int lane = tid & 63;
  const int w = tid >> 6;
  const int wr = w >> 1, wc = w & 1;     // wave tile 64 x BN/2
  const int fr = lane & 15, fq = lane >> 4;
  // XCD swizzle: hw assigns lid%8 -> XCD; give each XCD a contiguous range
  const int lid = blockIdx.y * gridDim.x + blockIdx.x;
  const int total = gridDim.x * gridDim.y;
  const int nlid = (lid >> 3) + (lid & 7) * (total >> 3);
  const int bx = nlid & 31;             // gridDim.x == 32 for both GEMMs
  const int by = nlid >> 5;
  const int m0 = bx * 128;
  const int n0 = by * BN;
  const int NFR = BN / 32;               // B frags per wave

  f32x4 acc[4][BN / 32] = {};
  const int NT = K >> 6;

  for (int kt = 0; kt < NT; ++kt) {
    const int k0 = kt << 6;
    __syncthreads();
    #pragma unroll
    for (int p = 0; p < 4; ++p) {        // A: 1024 chunks
      int c = p * 256 + tid;
      int row = c >> 3, cs = (c & 7) ^ (row & 7);
      gload16(&A[(size_t)(m0 + row) * K + k0 + cs * 8], &As[(p * 256 + w * 64) * 8]);
    }
    #pragma unroll
    for (int p = 0; p < BN / 32; ++p) {  // B: BN*8 chunks
      int c = p * 256 + tid;
      int row = c >> 3, cs = (c & 7) ^ (row & 7);
      gload16(&B[(size_t)(n0 + row) * K + k0 + cs * 8], &Bs[(p * 256 + w * 64) * 8]);
    }
    __syncthreads();
    #pragma unroll
    for (int kk = 0; kk < 2; ++kk) {
      bf16x8 af[4], bfr[BN / 32];
      #pragma unroll
      for (int mf = 0; mf < 4; ++mf) {
        int row = wr * 64 + mf * 16 + fr;
        af[mf] = *(const bf16x8*)&As[row * 64 + ((kk * 32 + fq * 8) ^ ((fr & 7) << 3))];
      }
      #pragma unroll
      for (int nf = 0; nf < NFR; ++nf) {
        int row = wc * (BN / 2) + nf * 16 + fr;
        bfr[nf] = *(const bf16x8*)&Bs[row * 64 + ((kk * 32 + fq * 8) ^ ((fr & 7) << 3))];
      }
      __builtin_amdgcn_s_setprio(1);
      #pragma unroll
      for (int mf = 0; mf < 4; ++mf)
        #pragma unroll
        for (int nf = 0; nf < NFR; ++nf)
          acc[mf][nf] = __builtin_amdgcn_mfma_f32_16x16x32_bf16(af[mf], bfr[nf], acc[mf][nf], 0, 0, 0);
      __builtin_amdgcn_s_setprio(0);
    }
  }

  if (EPI == 0) {
    const int nbase = n0 + wc * 64;        // aligned 64: one (which, head)
    const int which = nbase >> 10;
    const int h = (nbase & 1023) >> 6;
    const int b = m0 >> 11;                // whole block in one batch
    __bf16* base0 = (__bf16*)Cout + (size_t)which * (4u << 20);
    if (which < 2) {
      // Q / K with RoPE (Q also scaled)
      const float scale = (which == 0) ? QSCALE : 1.0f;
      __bf16* dst = base0 + ((size_t)(b * NH + h)) * SEQ * DKH;
      #pragma unroll
      for (int mf = 0; mf < 4; ++mf) {
        #pragma unroll
        for (int j = 0; j < 4; ++j) {
          int s = (m0 & (SEQ - 1)) + wr * 64 + mf * 16 + fq * 4 + j;
          #pragma unroll
          for (int nf = 0; nf < 2; ++nf) {
            int i = nf * 16 + fr;
            f32x2 cs = ((const f32x2*)tab)[s * 32 + i];
            float a = acc[mf][nf][j], bb = acc[mf][nf + 2][j];
            dst[(size_t)s * DKH + i]      = (__bf16)((a * cs[0] - bb * cs[1]) * scale);
            dst[(size_t)s * DKH + i + 32] = (__bf16)((bb * cs[0] + a * cs[1]) * scale);
          }
        }
      }
    } else {
      // V transposed + key-permuted: Vt[bh][dk][pi(s)]
      __bf16* dst = base0 + ((size_t)(b * NH + h)) * DKH * SEQ;
      #pragma unroll
      for (int mf = 0; mf < 4; ++mf) {
        #pragma unroll
        for (int nf = 0; nf < 4; ++nf) {
          int dk = nf * 16 + fr;
          #pragma unroll
          for (int j = 0; j < 4; ++j) {
            int sp = (m0 & (SEQ - 1)) + wr * 64 + (mf >> 1) * 32 + fq * 8 + (mf & 1) * 4 + j;
            dst[(size_t)dk * SEQ + sp] = (__bf16)acc[mf][nf][j];
          }
        }
      }
    }
  } else {
    #pragma unroll
    for (int mf = 0; mf < 4; ++mf)
      #pragma unroll
      for (int nf = 0; nf < NFR; ++nf)
        #pragma unroll
        for (int j = 0; j < 4; ++j) {
          int m = m0 + wr * 64 + mf * 16 + fq * 4 + j;
          int n = n0 + wc * (BN / 2) + nf * 16 + fr;
          ((float*)Cout)[(size_t)m * N + n] = acc[mf][nf][j];
        }
  }
}

// ---------------- causal flash attention, KVBLK=128, 9-iter blocks --------
// 512 blocks (32 bh x 16 slots), 512 threads = 8 waves, 128-row q-tiles.
// XCD remap: 16 slots of each bh land on one XCD. KV staged 128 keys/iter
// (2-deep, one barrier/iter), consumed as two 64-key sub-steps.
// Causal split-K in 128-units:
//   slot 0..7  (A): own tile qa: kv128 0..qa, flush; help qb=15-qa: kv 9..15-qa.
//   slot 8..15 (B): tile qb=slot: kv128 0..8.
// l accumulated as a 5th PV column (P x ones_B -> C[q][0]); no VALU adds.
// Split-K fixup FUSED: second-finishing block of each (bh,qb) pair combines
// P0+P1 partials and writes Ab rows 1024..2047 (flag + device fences).
__launch_bounds__(512, 4)
__global__ void attn_causal(const __bf16* __restrict__ Qg, const __bf16* __restrict__ Kg,
                            const __bf16* __restrict__ Vtg, __bf16* __restrict__ Out,
                            float* __restrict__ P0, float* __restrict__ P1,
                            float* __restrict__ L0, float* __restrict__ L1,
                            int* __restrict__ flags) {
  __shared__ __bf16 Ks[2][128 * 64];    // [t][d] swizzled (32KB)
  __shared__ __bf16 Vts[2][64 * 128];   // [d][slot] swizzled (32KB)
  __shared__ int oldf;
  const int tid = threadIdx.x;
  const int lane = tid & 63;
  const int w = tid >> 6;
  const int fr = lane & 15, fq = lane >> 4;
  // XCD remap: raw%8 == XCD; contiguous 64 nlids (4 bh) per XCD
  const int r = blockIdx.x;
  const int nlid = (r & 7) * 64 + (r >> 3);
  const int bh = nlid >> 4;
  const int slot = nlid & 15;
  const bool isA = slot < 8;
  const int qa = slot;                          // valid when isA
  const int qb = isA ? (15 - slot) : slot;      // 8..15
  const int sw  = isA ? (qa + 1) : 99;          // phase-switch iteration
  const int off = isA ? (8 - qa) : 0;           // kvt = it<sw ? it : it+off
  const int nst = isA ? 8 : 9;                  // iters that stage/compute
  const int b = bh >> 4, h = bh & 15;
  const __bf16* Qh = Qg + (size_t)bh * SEQ * DKH;
  const __bf16* Kh = Kg + (size_t)bh * SEQ * DKH;
  const __bf16* Vth = Vtg + (size_t)bh * DKH * SEQ;

  int qrow_lo = (isA ? qa : qb) * 128 + w * 16;

  // staging geometry (per-thread invariant), 1024 chunks per tile, 2 passes
  const int ck0 = tid, ck1 = 512 + tid;
  const int kr0 = ck0 >> 3, kc0 = ((ck0 & 7) ^ (kr0 & 7)) * 8;
  const int kr1 = ck1 >> 3, kc1 = ((ck1 & 7) ^ (kr1 & 7)) * 8;
  const int vd0 = ck0 >> 4, vk0 = (((ck0 & 15) & 8) | (((ck0 & 15) ^ vd0) & 7)) * 8;
  const int vd1 = ck1 >> 4, vk1 = (((ck1 & 15) & 8) | (((ck1 & 15) ^ vd1) & 7)) * 8;

#define STAGE(buf, kvt) {                                                     \
    const int ts_ = (kvt) << 7;                                               \
    gload16(&Kh[(size_t)(ts_ + kr0) * DKH + kc0], &Ks[buf][(w * 64) * 8]);    \
    gload16(&Kh[(size_t)(ts_ + kr1) * DKH + kc1], &Ks[buf][(512 + w * 64) * 8]); \
    gload16(&Vth[(size_t)vd0 * SEQ + ts_ + vk0], &Vts[buf][(w * 64) * 8]);    \
    gload16(&Vth[(size_t)vd1 * SEQ + ts_ + vk1], &Vts[buf][(512 + w * 64) * 8]); }

  bf16x8 qf[2];
  #pragma unroll
  for (int kk = 0; kk < 2; ++kk)
    qf[kk] = *(const bf16x8*)&Qh[(size_t)(qrow_lo + fr) * DKH + kk * 32 + fq * 8];

  // ones B-fragment: B[k][0]=1 -> C[q][0] = sum_k P[q][k] = l
  bf16x8 vones;
  #pragma unroll
  for (int e = 0; e < 8; ++e) vones[e] = (fr == 0) ? (__bf16)1.0f : (__bf16)0.0f;

  f32x4 Oa[4] = {};
  f32x4 Oa5 = {};                       // l column

  // prologue: stage kv128 tile 0
  STAGE(0, 0);
  __syncthreads();

  for (int it = 0; it < 9; ++it) {
    const int cur = it & 1;
    if (it + 1 < nst) {
      const int nx = it + 1;
      const int kvn = (nx < sw) ? nx : nx + off;
      STAGE(cur ^ 1, kvn);
    }
    if (isA && it == sw) {
      // ---- flush band-A rows (complete): normalize, write to Ab ----
      float rl[4];
      #pragma unroll
      for (int j = 0; j < 4; ++j)
        rl[j] = 1.0f / __shfl(Oa5[j], fq << 4);
      #pragma unroll
      for (int nf = 0; nf < 4; ++nf)
        #pragma unroll
        for (int j = 0; j < 4; ++j) {
          int qr = qrow_lo + fq * 4 + j;
          Out[((size_t)(b * SEQ) + qr) * DM + h * DKH + nf * 16 + fr] =
              (__bf16)(Oa[nf][j] * rl[j]);
        }
      // ---- switch to help band B ----
      #pragma unroll
      for (int nf = 0; nf < 4; ++nf) Oa[nf] = (f32x4){0.f, 0.f, 0.f, 0.f};
      Oa5 = (f32x4){0.f, 0.f, 0.f, 0.f};
      qrow_lo = qb * 128 + w * 16;
      #pragma unroll
      for (int kk = 0; kk < 2; ++kk)
        qf[kk] = *(const bf16x8*)&Qh[(size_t)(qrow_lo + fr) * DKH + kk * 32 + fq * 8];
    }
    if (it < nst) {
      const int kvt = (it < sw) ? it : it + off;
      #pragma unroll
      for (int sub = 0; sub < 2; ++sub) {
        const int ts = (kvt << 7) + (sub << 6);
        if (ts > qrow_lo + 15) continue;
        // ---- QK^T swapped: sacc[nf] = K_frag x Q_frag ----
        f32x4 sacc[4] = {};
        __builtin_amdgcn_s_setprio(1);
        #pragma unroll
        for (int kk = 0; kk < 2; ++kk) {
          #pragma unroll
          for (int nf = 0; nf < 4; ++nf) {
            int krow = (sub << 6) + nf * 16 + fr;
            bf16x8 kf = *(const bf16x8*)&Ks[cur][krow * 64 + ((kk * 32 + fq * 8) ^ ((fr & 7) << 3))];
            sacc[nf] = __builtin_amdgcn_mfma_f32_16x16x32_bf16(kf, qf[kk], sacc[nf], 0, 0, 0);
          }
        }
        __builtin_amdgcn_s_setprio(0);
        // ---- P = exp2(s); mask only on diagonal sub-tiles ----
        const bool need_mask = (ts + 63 > qrow_lo);
        if (need_mask) {
          const int qr = qrow_lo + fr;
          #pragma unroll
          for (int nf = 0; nf < 4; ++nf) {
            #pragma unroll
            for (int j = 0; j < 4; ++j) {
              float v = sacc[nf][j];
              int tc = ts + nf * 16 + fq * 4 + j;
              if (tc > qr) v = -INFINITY;
              sacc[nf][j] = exp2f(v);
            }
          }
        } else {
          #pragma unroll
          for (int nf = 0; nf < 4; ++nf) {
            #pragma unroll
            for (int j = 0; j < 4; ++j)
              sacc[nf][j] = exp2f(sacc[nf][j]);
          }
        }
        // ---- pack P to PV A-fragments (pure register) ----
        bf16x8 pa[2];
        #pragma unroll
        for (int kk = 0; kk < 2; ++kk)
          #pragma unroll
          for (int e = 0; e < 8; ++e)
            pa[kk][e] = (__bf16)sacc[2 * kk + (e >> 2)][e & 3];
        // ---- PV (+ l column) ----
        __builtin_amdgcn_s_setprio(1);
        #pragma unroll
        for (int kk = 0; kk < 2; ++kk) {
          #pragma unroll
          for (int nf = 0; nf < 4; ++nf) {
            int d = nf * 16 + fr;
            bf16x8 vf = *(const bf16x8*)&Vts[cur][d * 128 + (sub << 6) +
                         (((kk * 4 + fq) ^ (fr & 7)) << 3)];
            Oa[nf] = __builtin_amdgcn_mfma_f32_16x16x32_bf16(pa[kk], vf, Oa[nf], 0, 0, 0);
          }
          Oa5 = __builtin_amdgcn_mfma_f32_16x16x32_bf16(pa[kk], vones, Oa5, 0, 0, 0);
        }
        __builtin_amdgcn_s_setprio(0);
      }
    }
    __syncthreads();
  }
#undef STAGE
  // ---- write PARTIAL (O, l) for band-B rows ----
  float* P = isA ? P1 : P0;
  float* L = isA ? L1 : L0;
  const int tidx = (bh << 3) + (qb - 8);           // 0..255
  const int rbase = tidx << 7;                     // *128 rows
  if (fr == 0) {
    #pragma unroll
    for (int j = 0; j < 4; ++j)
      L[rbase + w * 16 + fq * 4 + j] = Oa5[j];
  }
  #pragma unroll
  for (int nf = 0; nf < 4; ++nf)
    #pragma unroll
    for (int j = 0; j < 4; ++j)
      P[(size_t)(rbase + w * 16 + fq * 4 + j) * 64 + nf * 16 + fr] = Oa[nf][j];

  // ---- fused split-K fixup: second finisher combines ----
  __threadfence();
  if (tid == 0) oldf = atomicAdd(&flags[tidx], 1);
  __syncthreads();
  if (oldf == 1) {
    __threadfence();
    int row = tid >> 2, seg = tid & 3;
    int rid = rbase + row;
    float rl2 = 1.0f / (L0[rid] + L1[rid]);
    const float* p0 = P0 + (size_t)rid * 64 + seg * 16;
    const float* p1 = P1 + (size_t)rid * 64 + seg * 16;
    bf16x8 o0, o1;
    #pragma unroll
    for (int e = 0; e < 8; ++e) {
      o0[e] = (__bf16)((p0[e] + p1[e]) * rl2);
      o1[e] = (__bf16)((p0[e + 8] + p1[e + 8]) * rl2);
    }
    int s = 1024 + ((qb - 8) << 7) + row;
    __bf16* dst = Out + ((size_t)b * SEQ + s) * DM + h * DKH + seg * 16;
    *(bf16x8*)dst = o0;
    *(bf16x8*)(dst + 8) = o1;
  }
}

extern "C" void kernel_launch(void* const* d_in, const int* in_sizes, int n_in,
                              void* d_out, int out_size, void* d_ws, size_t ws_size,
                              hipStream_t stream) {
  const float* x  = (const float*)d_in[0];
  const float* Wq = (const float*)d_in[1];
  const float* Wk = (const float*)d_in[2];
  const float* Wv = (const float*)d_in[3];
  const float* Wo = (const float*)d_in[4];

  char* ws = (char*)d_ws;
  __bf16* xb  = (__bf16*)(ws);                       // 8 MB
  __bf16* wqb = (__bf16*)(ws + ( 8u << 20));         // Wq,Wk,Wv,Wo contiguous
  __bf16* wob = (__bf16*)(ws + (14u << 20));
  __bf16* Qb  = (__bf16*)(ws + (16u << 20));         // [BH][S][64]
  __bf16* Kb  = (__bf16*)(ws + (24u << 20));         // = Qb + 4M elems
  __bf16* Vtb = (__bf16*)(ws + (32u << 20));         // = Qb + 8M elems, [BH][64][S] permuted
  __bf16* Ab  = (__bf16*)(ws + (40u << 20));         // [B*S][1024]
  float*  tab = (float*)(ws + (48u << 20));          // [SEQ][32] float2 (512 KB)
  float*  L0  = (float*)(ws + (49u << 20));          // 32768 floats (128 KB)
  float*  L1  = (float*)(ws + (49u << 20) + (1u << 18));
  int*  flags = (int*)(ws + (49u << 20) + (1u << 19));  // 256 ints
  // split-K O-partials live in d_out (16 MB scratch, overwritten by WO GEMM)
  float* P0 = (float*)d_out;                          // 2M floats
  float* P1 = P0 + (32768 * 64);                      // 2M floats

  prep<<<dim3(4353), dim3(256), 0, stream>>>(x, Wq, Wk, Wv, Wo, xb, wqb, tab, flags);

  // merged QKV projection with fused RoPE/scale/V-transpose-permute epilogue
  gemm_bt<0, 128><<<dim3(32, 24), dim3(256), 0, stream>>>(xb, wqb, Qb, BATCH * SEQ, 3 * DM, DM, tab);

  attn_causal<<<dim3(512), dim3(512), 0, stream>>>(Qb, Kb, Vtb, Ab, P0, P1, L0, L1, flags);

  gemm_bt<1, 64><<<dim3(32, 16), dim3(256), 0, stream>>>(Ab, wob, d_out, BATCH * SEQ, DM, DM, nullptr);
}

// Round 18
// 95.341 us; speedup vs baseline: 2.7456x; 2.7456x over previous
//
#include <hip/hip_runtime.h>
#include <hip/hip_bf16.h>

#define BATCH 2
#define SEQ 2048
#define DM 1024
#define NH 16
#define DKH 64

typedef __attribute__((ext_vector_type(8))) __bf16 bf16x8;
typedef __attribute__((ext_vector_type(4))) float f32x4;
typedef __attribute__((ext_vector_type(2))) float f32x2;
typedef __attribute__((ext_vector_type(8))) unsigned short ushort8;

__device__ __forceinline__ void gload16(const void* g, void* l) {
  __builtin_amdgcn_global_load_lds(
      (const __attribute__((address_space(1))) void*)g,
      (__attribute__((address_space(3))) void*)l, 16, 0, 0);
}

// ------ merged prep: x cast | weight casts | RoPE table, one launch -------
__global__ void prep(const float* __restrict__ x,
                     const float* __restrict__ w0, const float* __restrict__ w1,
                     const float* __restrict__ w2, const float* __restrict__ w3,
                     __bf16* __restrict__ xb, __bf16* __restrict__ wb,
                     float* __restrict__ tab) {
  const int bid = blockIdx.x, tid = threadIdx.x;
  if (bid < 2048) {                       // x: 4M elems, 512K chunks of 8
    int i = bid * 256 + tid;
    f32x4 a = ((const f32x4*)x)[2 * i], b = ((const f32x4*)x)[2 * i + 1];
    bf16x8 o;
    o[0]=(__bf16)a[0]; o[1]=(__bf16)a[1]; o[2]=(__bf16)a[2]; o[3]=(__bf16)a[3];
    o[4]=(__bf16)b[0]; o[5]=(__bf16)b[1]; o[6]=(__bf16)b[2]; o[7]=(__bf16)b[3];
    ((bf16x8*)xb)[i] = o;
  } else if (bid < 4096) {                // weights: 4 x 1M elems contiguous dst
    int i = (bid - 2048) * 256 + tid;     // [0, 512K)
    int wi = i >> 17;
    const float* src = (wi == 0) ? w0 : (wi == 1) ? w1 : (wi == 2) ? w2 : w3;
    int li = i & 131071;
    f32x4 a = ((const f32x4*)src)[2 * li], b = ((const f32x4*)src)[2 * li + 1];
    bf16x8 o;
    o[0]=(__bf16)a[0]; o[1]=(__bf16)a[1]; o[2]=(__bf16)a[2]; o[3]=(__bf16)a[3];
    o[4]=(__bf16)b[0]; o[5]=(__bf16)b[1]; o[6]=(__bf16)b[2]; o[7]=(__bf16)b[3];
    ((bf16x8*)wb)[i] = o;
  } else {                                // RoPE table: 65536 (s,i) entries
    int idx = (bid - 4096) * 256 + tid;
    int s = idx >> 5, ii = idx & 31;
    float theta = exp2f((float)ii * -0.41524101186092029f);  // 10000^(-i/32)
    float sn, c;
    sincosf((float)s * theta, &sn, &c);
    tab[2 * idx] = c;
    tab[2 * idx + 1] = sn;
  }
}

#define QSCALE 0.1803368801111137f   // 0.125 * log2(e)

// ---------------- GEMM: C[m][n] = sum_k A[m][k] * B[n][k] -----------------
// m97 structure: 128xBN tile, BK=64, single-buffered 32KB LDS, 3 blocks/CU.
// XCD-aware block swizzle (grid linear count divisible by 8; gridDim.x==32).
// EPI 0 (BN=128): QKV projection, N=3072. Q (RoPE*QSCALE), K (RoPE) ->
//        [BH][S][64]; V -> transposed + KEY-PERMUTED [BH][64][S].
// EPI 1 (BN=64): fp32 row-major M x N.
template<int EPI, int BN>
__launch_bounds__(256, 3)
__global__ void gemm_bt(const __bf16* __restrict__ A, const __bf16* __restrict__ B,
                        void* __restrict__ Cout, int M, int N, int K,
                        const float* __restrict__ tab) {
  __shared__ __bf16 As[128 * 64];
  __shared__ __bf16 Bs[BN * 64];
  const int tid = threadIdx.x;
  const int lane = tid & 63;
  const int w = tid >> 6;
  const int wr = w >> 1, wc = w & 1;     // wave tile 64 x BN/2
  const int fr = lane & 15, fq = lane >> 4;
  // XCD swizzle: hw assigns lid%8 -> XCD; give each XCD a contiguous range
  const int lid = blockIdx.y * gridDim.x + blockIdx.x;
  const int total = gridDim.x * gridDim.y;
  const int nlid = (lid >> 3) + (lid & 7) * (total >> 3);
  const int bx = nlid & 31;             // gridDim.x == 32 for both GEMMs
  const int by = nlid >> 5;
  const int m0 = bx * 128;
  const int n0 = by * BN;
  const int NFR = BN / 32;               // B frags per wave

  f32x4 acc[4][BN / 32] = {};
  const int NT = K >> 6;

  for (int kt = 0; kt < NT; ++kt) {
    const int k0 = kt << 6;
    __syncthreads();
    #pragma unroll
    for (int p = 0; p < 4; ++p) {        // A: 1024 chunks
      int c = p * 256 + tid;
      int row = c >> 3, cs = (c & 7) ^ (row & 7);
      gload16(&A[(size_t)(m0 + row) * K + k0 + cs * 8], &As[(p * 256 + w * 64) * 8]);
    }
    #pragma unroll
    for (int p = 0; p < BN / 32; ++p) {  // B: BN*8 chunks
      int c = p * 256 + tid;
      int row = c >> 3, cs = (c & 7) ^ (row & 7);
      gload16(&B[(size_t)(n0 + row) * K + k0 + cs * 8], &Bs[(p * 256 + w * 64) * 8]);
    }
    __syncthreads();
    #pragma unroll
    for (int kk = 0; kk < 2; ++kk) {
      bf16x8 af[4], bfr[BN / 32];
      #pragma unroll
      for (int mf = 0; mf < 4; ++mf) {
        int row = wr * 64 + mf * 16 + fr;
        af[mf] = *(const bf16x8*)&As[row * 64 + ((kk * 32 + fq * 8) ^ ((fr & 7) << 3))];
      }
      #pragma unroll
      for (int nf = 0; nf < NFR; ++nf) {
        int row = wc * (BN / 2) + nf * 16 + fr;
        bfr[nf] = *(const bf16x8*)&Bs[row * 64 + ((kk * 32 + fq * 8) ^ ((fr & 7) << 3))];
      }
      __builtin_amdgcn_s_setprio(1);
      #pragma unroll
      for (int mf = 0; mf < 4; ++mf)
        #pragma unroll
        for (int nf = 0; nf < NFR; ++nf)
          acc[mf][nf] = __builtin_amdgcn_mfma_f32_16x16x32_bf16(af[mf], bfr[nf], acc[mf][nf], 0, 0, 0);
      __builtin_amdgcn_s_setprio(0);
    }
  }

  if (EPI == 0) {
    const int nbase = n0 + wc * 64;        // aligned 64: one (which, head)
    const int which = nbase >> 10;
    const int h = (nbase & 1023) >> 6;
    const int b = m0 >> 11;                // whole block in one batch
    __bf16* base0 = (__bf16*)Cout + (size_t)which * (4u << 20);
    if (which < 2) {
      // Q / K with RoPE (Q also scaled)
      const float scale = (which == 0) ? QSCALE : 1.0f;
      __bf16* dst = base0 + ((size_t)(b * NH + h)) * SEQ * DKH;
      #pragma unroll
      for (int mf = 0; mf < 4; ++mf) {
        #pragma unroll
        for (int j = 0; j < 4; ++j) {
          int s = (m0 & (SEQ - 1)) + wr * 64 + mf * 16 + fq * 4 + j;
          #pragma unroll
          for (int nf = 0; nf < 2; ++nf) {
            int i = nf * 16 + fr;
            f32x2 cs = ((const f32x2*)tab)[s * 32 + i];
            float a = acc[mf][nf][j], bb = acc[mf][nf + 2][j];
            dst[(size_t)s * DKH + i]      = (__bf16)((a * cs[0] - bb * cs[1]) * scale);
            dst[(size_t)s * DKH + i + 32] = (__bf16)((bb * cs[0] + a * cs[1]) * scale);
          }
        }
      }
    } else {
      // V transposed + key-permuted: Vt[bh][dk][pi(s)]
      __bf16* dst = base0 + ((size_t)(b * NH + h)) * DKH * SEQ;
      #pragma unroll
      for (int mf = 0; mf < 4; ++mf) {
        #pragma unroll
        for (int nf = 0; nf < 4; ++nf) {
          int dk = nf * 16 + fr;
          #pragma unroll
          for (int j = 0; j < 4; ++j) {
            int sp = (m0 & (SEQ - 1)) + wr * 64 + (mf >> 1) * 32 + fq * 8 + (mf & 1) * 4 + j;
            dst[(size_t)dk * SEQ + sp] = (__bf16)acc[mf][nf][j];
          }
        }
      }
    }
  } else {
    #pragma unroll
    for (int mf = 0; mf < 4; ++mf)
      #pragma unroll
      for (int nf = 0; nf < NFR; ++nf)
        #pragma unroll
        for (int j = 0; j < 4; ++j) {
          int m = m0 + wr * 64 + mf * 16 + fq * 4 + j;
          int n = n0 + wc * (BN / 2) + nf * 16 + fr;
          ((float*)Cout)[(size_t)m * N + n] = acc[mf][nf][j];
        }
  }
}

// ---------------- causal flash attention, KVBLK=128, 9-iter blocks --------
// 512 blocks (32 bh x 16 slots), 512 threads = 8 waves, 128-row q-tiles.
// XCD remap: 16 slots of each bh land on one XCD. KV staged 128 keys/iter
// (2-deep, one barrier/iter), consumed as two 64-key sub-steps.
// Causal split-K in 128-units:
//   slot 0..7  (A): own tile qa: kv128 0..qa, flush; help qb=15-qa: kv 9..15-qa.
//   slot 8..15 (B): tile qb=slot: kv128 0..8.
// l accumulated as a 5th PV column (P x ones_B -> C[q][0]); no VALU adds.
// NO device fences/atomics in this kernel (round-17 lesson: __threadfence
// per block serializes ~0.33us x 512 blocks); combine is a separate launch.
__launch_bounds__(512, 4)
__global__ void attn_causal(const __bf16* __restrict__ Qg, const __bf16* __restrict__ Kg,
                            const __bf16* __restrict__ Vtg, __bf16* __restrict__ Out,
                            float* __restrict__ P0, float* __restrict__ P1,
                            float* __restrict__ L0, float* __restrict__ L1) {
  __shared__ __bf16 Ks[2][128 * 64];    // [t][d] swizzled (32KB)
  __shared__ __bf16 Vts[2][64 * 128];   // [d][slot] swizzled (32KB)
  const int tid = threadIdx.x;
  const int lane = tid & 63;
  const int w = tid >> 6;
  const int fr = lane & 15, fq = lane >> 4;
  // XCD remap: raw%8 == XCD; contiguous 64 nlids (4 bh) per XCD
  const int r = blockIdx.x;
  const int nlid = (r & 7) * 64 + (r >> 3);
  const int bh = nlid >> 4;
  const int slot = nlid & 15;
  const bool isA = slot < 8;
  const int qa = slot;                          // valid when isA
  const int qb = isA ? (15 - slot) : slot;      // 8..15
  const int sw  = isA ? (qa + 1) : 99;          // phase-switch iteration
  const int off = isA ? (8 - qa) : 0;           // kvt = it<sw ? it : it+off
  const int nst = isA ? 8 : 9;                  // iters that stage/compute
  const int b = bh >> 4, h = bh & 15;
  const __bf16* Qh = Qg + (size_t)bh * SEQ * DKH;
  const __bf16* Kh = Kg + (size_t)bh * SEQ * DKH;
  const __bf16* Vth = Vtg + (size_t)bh * DKH * SEQ;

  int qrow_lo = (isA ? qa : qb) * 128 + w * 16;

  // staging geometry (per-thread invariant), 1024 chunks per tile, 2 passes
  const int ck0 = tid, ck1 = 512 + tid;
  const int kr0 = ck0 >> 3, kc0 = ((ck0 & 7) ^ (kr0 & 7)) * 8;
  const int kr1 = ck1 >> 3, kc1 = ((ck1 & 7) ^ (kr1 & 7)) * 8;
  const int vd0 = ck0 >> 4, vk0 = (((ck0 & 15) & 8) | (((ck0 & 15) ^ vd0) & 7)) * 8;
  const int vd1 = ck1 >> 4, vk1 = (((ck1 & 15) & 8) | (((ck1 & 15) ^ vd1) & 7)) * 8;

#define STAGE(buf, kvt) {                                                     \
    const int ts_ = (kvt) << 7;                                               \
    gload16(&Kh[(size_t)(ts_ + kr0) * DKH + kc0], &Ks[buf][(w * 64) * 8]);    \
    gload16(&Kh[(size_t)(ts_ + kr1) * DKH + kc1], &Ks[buf][(512 + w * 64) * 8]); \
    gload16(&Vth[(size_t)vd0 * SEQ + ts_ + vk0], &Vts[buf][(w * 64) * 8]);    \
    gload16(&Vth[(size_t)vd1 * SEQ + ts_ + vk1], &Vts[buf][(512 + w * 64) * 8]); }

  bf16x8 qf[2];
  #pragma unroll
  for (int kk = 0; kk < 2; ++kk)
    qf[kk] = *(const bf16x8*)&Qh[(size_t)(qrow_lo + fr) * DKH + kk * 32 + fq * 8];

  // ones B-fragment: B[k][0]=1 -> C[q][0] = sum_k P[q][k] = l
  bf16x8 vones;
  #pragma unroll
  for (int e = 0; e < 8; ++e) vones[e] = (fr == 0) ? (__bf16)1.0f : (__bf16)0.0f;

  f32x4 Oa[4] = {};
  f32x4 Oa5 = {};                       // l column

  // prologue: stage kv128 tile 0
  STAGE(0, 0);
  __syncthreads();

  for (int it = 0; it < 9; ++it) {
    const int cur = it & 1;
    if (it + 1 < nst) {
      const int nx = it + 1;
      const int kvn = (nx < sw) ? nx : nx + off;
      STAGE(cur ^ 1, kvn);
    }
    if (isA && it == sw) {
      // ---- flush band-A rows (complete): normalize, write to Ab ----
      float rl[4];
      #pragma unroll
      for (int j = 0; j < 4; ++j)
        rl[j] = 1.0f / __shfl(Oa5[j], fq << 4);
      #pragma unroll
      for (int nf = 0; nf < 4; ++nf)
        #pragma unroll
        for (int j = 0; j < 4; ++j) {
          int qr = qrow_lo + fq * 4 + j;
          Out[((size_t)(b * SEQ) + qr) * DM + h * DKH + nf * 16 + fr] =
              (__bf16)(Oa[nf][j] * rl[j]);
        }
      // ---- switch to help band B ----
      #pragma unroll
      for (int nf = 0; nf < 4; ++nf) Oa[nf] = (f32x4){0.f, 0.f, 0.f, 0.f};
      Oa5 = (f32x4){0.f, 0.f, 0.f, 0.f};
      qrow_lo = qb * 128 + w * 16;
      #pragma unroll
      for (int kk = 0; kk < 2; ++kk)
        qf[kk] = *(const bf16x8*)&Qh[(size_t)(qrow_lo + fr) * DKH + kk * 32 + fq * 8];
    }
    if (it < nst) {
      const int kvt = (it < sw) ? it : it + off;
      #pragma unroll
      for (int sub = 0; sub < 2; ++sub) {
        const int ts = (kvt << 7) + (sub << 6);
        if (ts > qrow_lo + 15) continue;
        // ---- QK^T swapped: sacc[nf] = K_frag x Q_frag ----
        f32x4 sacc[4] = {};
        __builtin_amdgcn_s_setprio(1);
        #pragma unroll
        for (int kk = 0; kk < 2; ++kk) {
          #pragma unroll
          for (int nf = 0; nf < 4; ++nf) {
            int krow = (sub << 6) + nf * 16 + fr;
            bf16x8 kf = *(const bf16x8*)&Ks[cur][krow * 64 + ((kk * 32 + fq * 8) ^ ((fr & 7) << 3))];
            sacc[nf] = __builtin_amdgcn_mfma_f32_16x16x32_bf16(kf, qf[kk], sacc[nf], 0, 0, 0);
          }
        }
        __builtin_amdgcn_s_setprio(0);
        // ---- P = exp2(s); mask only on diagonal sub-tiles ----
        const bool need_mask = (ts + 63 > qrow_lo);
        if (need_mask) {
          const int qr = qrow_lo + fr;
          #pragma unroll
          for (int nf = 0; nf < 4; ++nf) {
            #pragma unroll
            for (int j = 0; j < 4; ++j) {
              float v = sacc[nf][j];
              int tc = ts + nf * 16 + fq * 4 + j;
              if (tc > qr) v = -INFINITY;
              sacc[nf][j] = exp2f(v);
            }
          }
        } else {
          #pragma unroll
          for (int nf = 0; nf < 4; ++nf) {
            #pragma unroll
            for (int j = 0; j < 4; ++j)
              sacc[nf][j] = exp2f(sacc[nf][j]);
          }
        }
        // ---- pack P to PV A-fragments (pure register) ----
        bf16x8 pa[2];
        #pragma unroll
        for (int kk = 0; kk < 2; ++kk)
          #pragma unroll
          for (int e = 0; e < 8; ++e)
            pa[kk][e] = (__bf16)sacc[2 * kk + (e >> 2)][e & 3];
        // ---- PV (+ l column) ----
        __builtin_amdgcn_s_setprio(1);
        #pragma unroll
        for (int kk = 0; kk < 2; ++kk) {
          #pragma unroll
          for (int nf = 0; nf < 4; ++nf) {
            int d = nf * 16 + fr;
            bf16x8 vf = *(const bf16x8*)&Vts[cur][d * 128 + (sub << 6) +
                         (((kk * 4 + fq) ^ (fr & 7)) << 3)];
            Oa[nf] = __builtin_amdgcn_mfma_f32_16x16x32_bf16(pa[kk], vf, Oa[nf], 0, 0, 0);
          }
          Oa5 = __builtin_amdgcn_mfma_f32_16x16x32_bf16(pa[kk], vones, Oa5, 0, 0, 0);
        }
        __builtin_amdgcn_s_setprio(0);
      }
    }
    __syncthreads();
  }
#undef STAGE
  // ---- final: write PARTIAL (O, l) for band-B rows ----
  float* P = isA ? P1 : P0;
  float* L = isA ? L1 : L0;
  const int rbase = ((bh << 3) + (qb - 8)) << 7;   // *128 rows
  if (fr == 0) {
    #pragma unroll
    for (int j = 0; j < 4; ++j)
      L[rbase + w * 16 + fq * 4 + j] = Oa5[j];
  }
  #pragma unroll
  for (int nf = 0; nf < 4; ++nf)
    #pragma unroll
    for (int j = 0; j < 4; ++j)
      P[(size_t)(rbase + w * 16 + fq * 4 + j) * 64 + nf * 16 + fr] = Oa[nf][j];
}

// ---------------- combine split-K partials -> Ab rows 1024..2047 ----------
__global__ void combine(const float* __restrict__ P0, const float* __restrict__ P1,
                        const float* __restrict__ L0, const float* __restrict__ L1,
                        __bf16* __restrict__ Ab) {
  int t = blockIdx.x * blockDim.x + threadIdx.x;   // 262144
  int rowid = t >> 3, d0 = (t & 7) * 8;
  int bh = rowid >> 10, rem = rowid & 1023;
  int tq = rem >> 7, r = rem & 127;
  float rl = 1.0f / (L0[rowid] + L1[rowid]);
  const float* p0 = P0 + (size_t)rowid * 64 + d0;
  const float* p1 = P1 + (size_t)rowid * 64 + d0;
  f32x4 a0 = *(const f32x4*)p0, a1 = *(const f32x4*)(p0 + 4);
  f32x4 b0 = *(const f32x4*)p1, b1 = *(const f32x4*)(p1 + 4);
  bf16x8 o;
  #pragma unroll
  for (int e = 0; e < 4; ++e) {
    o[e]     = (__bf16)((a0[e] + b0[e]) * rl);
    o[e + 4] = (__bf16)((a1[e] + b1[e]) * rl);
  }
  int s = (tq + 8) * 128 + r;
  int b = bh >> 4, h = bh & 15;
  *(bf16x8*)&Ab[((size_t)b * SEQ + s) * DM + h * DKH + d0] = o;
}

extern "C" void kernel_launch(void* const* d_in, const int* in_sizes, int n_in,
                              void* d_out, int out_size, void* d_ws, size_t ws_size,
                              hipStream_t stream) {
  const float* x  = (const float*)d_in[0];
  const float* Wq = (const float*)d_in[1];
  const float* Wk = (const float*)d_in[2];
  const float* Wv = (const float*)d_in[3];
  const float* Wo = (const float*)d_in[4];

  char* ws = (char*)d_ws;
  __bf16* xb  = (__bf16*)(ws);                       // 8 MB
  __bf16* wqb = (__bf16*)(ws + ( 8u << 20));         // Wq,Wk,Wv,Wo contiguous
  __bf16* wob = (__bf16*)(ws + (14u << 20));
  __bf16* Qb  = (__bf16*)(ws + (16u << 20));         // [BH][S][64]
  __bf16* Kb  = (__bf16*)(ws + (24u << 20));         // = Qb + 4M elems
  __bf16* Vtb = (__bf16*)(ws + (32u << 20));         // = Qb + 8M elems, [BH][64][S] permuted
  __bf16* Ab  = (__bf16*)(ws + (40u << 20));         // [B*S][1024]
  float*  tab = (float*)(ws + (48u << 20));          // [SEQ][32] float2 (512 KB)
  float*  L0  = (float*)(ws + (49u << 20));          // 32768 floats (128 KB)
  float*  L1  = (float*)(ws + (49u << 20) + (1u << 18));
  // split-K O-partials live in d_out (16 MB scratch, overwritten by WO GEMM)
  float* P0 = (float*)d_out;                          // 2M floats
  float* P1 = P0 + (32768 * 64);                      // 2M floats

  prep<<<dim3(4352), dim3(256), 0, stream>>>(x, Wq, Wk, Wv, Wo, xb, wqb, tab);

  // merged QKV projection with fused RoPE/scale/V-transpose-permute epilogue
  gemm_bt<0, 128><<<dim3(32, 24), dim3(256), 0, stream>>>(xb, wqb, Qb, BATCH * SEQ, 3 * DM, DM, tab);

  attn_causal<<<dim3(512), dim3(512), 0, stream>>>(Qb, Kb, Vtb, Ab, P0, P1, L0, L1);

  combine<<<dim3(1024), dim3(256), 0, stream>>>(P0, P1, L0, L1, Ab);

  gemm_bt<1, 64><<<dim3(32, 16), dim3(256), 0, stream>>>(Ab, wob, d_out, BATCH * SEQ, DM, DM, nullptr);
}

// Round 19
// 94.515 us; speedup vs baseline: 2.7696x; 1.0087x over previous
//
#include <hip/hip_runtime.h>
#include <hip/hip_bf16.h>

#define BATCH 2
#define SEQ 2048
#define DM 1024
#define NH 16
#define DKH 64

typedef __attribute__((ext_vector_type(8))) __bf16 bf16x8;
typedef __attribute__((ext_vector_type(4))) float f32x4;
typedef __attribute__((ext_vector_type(2))) float f32x2;
typedef __attribute__((ext_vector_type(8))) unsigned short ushort8;

__device__ __forceinline__ void gload16(const void* g, void* l) {
  __builtin_amdgcn_global_load_lds(
      (const __attribute__((address_space(1))) void*)g,
      (__attribute__((address_space(3))) void*)l, 16, 0, 0);
}

// ------ merged prep: x cast | weight casts | RoPE table, one launch -------
__global__ void prep(const float* __restrict__ x,
                     const float* __restrict__ w0, const float* __restrict__ w1,
                     const float* __restrict__ w2, const float* __restrict__ w3,
                     __bf16* __restrict__ xb, __bf16* __restrict__ wb,
                     float* __restrict__ tab) {
  const int bid = blockIdx.x, tid = threadIdx.x;
  if (bid < 2048) {                       // x: 4M elems, 512K chunks of 8
    int i = bid * 256 + tid;
    f32x4 a = ((const f32x4*)x)[2 * i], b = ((const f32x4*)x)[2 * i + 1];
    bf16x8 o;
    o[0]=(__bf16)a[0]; o[1]=(__bf16)a[1]; o[2]=(__bf16)a[2]; o[3]=(__bf16)a[3];
    o[4]=(__bf16)b[0]; o[5]=(__bf16)b[1]; o[6]=(__bf16)b[2]; o[7]=(__bf16)b[3];
    ((bf16x8*)xb)[i] = o;
  } else if (bid < 4096) {                // weights: 4 x 1M elems contiguous dst
    int i = (bid - 2048) * 256 + tid;     // [0, 512K)
    int wi = i >> 17;
    const float* src = (wi == 0) ? w0 : (wi == 1) ? w1 : (wi == 2) ? w2 : w3;
    int li = i & 131071;
    f32x4 a = ((const f32x4*)src)[2 * li], b = ((const f32x4*)src)[2 * li + 1];
    bf16x8 o;
    o[0]=(__bf16)a[0]; o[1]=(__bf16)a[1]; o[2]=(__bf16)a[2]; o[3]=(__bf16)a[3];
    o[4]=(__bf16)b[0]; o[5]=(__bf16)b[1]; o[6]=(__bf16)b[2]; o[7]=(__bf16)b[3];
    ((bf16x8*)wb)[i] = o;
  } else {                                // RoPE table: 65536 (s,i) entries
    int idx = (bid - 4096) * 256 + tid;
    int s = idx >> 5, ii = idx & 31;
    float theta = exp2f((float)ii * -0.41524101186092029f);  // 10000^(-i/32)
    float sn, c;
    sincosf((float)s * theta, &sn, &c);
    tab[2 * idx] = c;
    tab[2 * idx + 1] = sn;
  }
}

#define QSCALE 0.1803368801111137f   // 0.125 * log2(e)

// ---------------- GEMM: C[m][n] = sum_k A[m][k] * B[n][k] -----------------
// m97 structure: 128xBN tile, BK=64, single-buffered 32KB LDS, 3 blocks/CU.
// XCD-aware block swizzle (grid linear count divisible by 8; gridDim.x==32).
// EPI 0 (BN=128): QKV projection, N=3072. Q (RoPE*QSCALE), K (RoPE) ->
//        [BH][S][64]; V -> transposed + KEY-PERMUTED [BH][64][S].
// EPI 1 (BN=64): fp32 row-major M x N.
template<int EPI, int BN>
__launch_bounds__(256, 3)
__global__ void gemm_bt(const __bf16* __restrict__ A, const __bf16* __restrict__ B,
                        void* __restrict__ Cout, int M, int N, int K,
                        const float* __restrict__ tab) {
  __shared__ __bf16 As[128 * 64];
  __shared__ __bf16 Bs[BN * 64];
  const int tid = threadIdx.x;
  const int lane = tid & 63;
  const int w = tid >> 6;
  const int wr = w >> 1, wc = w & 1;     // wave tile 64 x BN/2
  const int fr = lane & 15, fq = lane >> 4;
  // XCD swizzle: hw assigns lid%8 -> XCD; give each XCD a contiguous range
  const int lid = blockIdx.y * gridDim.x + blockIdx.x;
  const int total = gridDim.x * gridDim.y;
  const int nlid = (lid >> 3) + (lid & 7) * (total >> 3);
  const int bx = nlid & 31;             // gridDim.x == 32 for both GEMMs
  const int by = nlid >> 5;
  const int m0 = bx * 128;
  const int n0 = by * BN;
  const int NFR = BN / 32;               // B frags per wave

  f32x4 acc[4][BN / 32] = {};
  const int NT = K >> 6;

  for (int kt = 0; kt < NT; ++kt) {
    const int k0 = kt << 6;
    __syncthreads();
    #pragma unroll
    for (int p = 0; p < 4; ++p) {        // A: 1024 chunks
      int c = p * 256 + tid;
      int row = c >> 3, cs = (c & 7) ^ (row & 7);
      gload16(&A[(size_t)(m0 + row) * K + k0 + cs * 8], &As[(p * 256 + w * 64) * 8]);
    }
    #pragma unroll
    for (int p = 0; p < BN / 32; ++p) {  // B: BN*8 chunks
      int c = p * 256 + tid;
      int row = c >> 3, cs = (c & 7) ^ (row & 7);
      gload16(&B[(size_t)(n0 + row) * K + k0 + cs * 8], &Bs[(p * 256 + w * 64) * 8]);
    }
    __syncthreads();
    #pragma unroll
    for (int kk = 0; kk < 2; ++kk) {
      bf16x8 af[4], bfr[BN / 32];
      #pragma unroll
      for (int mf = 0; mf < 4; ++mf) {
        int row = wr * 64 + mf * 16 + fr;
        af[mf] = *(const bf16x8*)&As[row * 64 + ((kk * 32 + fq * 8) ^ ((fr & 7) << 3))];
      }
      #pragma unroll
      for (int nf = 0; nf < NFR; ++nf) {
        int row = wc * (BN / 2) + nf * 16 + fr;
        bfr[nf] = *(const bf16x8*)&Bs[row * 64 + ((kk * 32 + fq * 8) ^ ((fr & 7) << 3))];
      }
      __builtin_amdgcn_s_setprio(1);
      #pragma unroll
      for (int mf = 0; mf < 4; ++mf)
        #pragma unroll
        for (int nf = 0; nf < NFR; ++nf)
          acc[mf][nf] = __builtin_amdgcn_mfma_f32_16x16x32_bf16(af[mf], bfr[nf], acc[mf][nf], 0, 0, 0);
      __builtin_amdgcn_s_setprio(0);
    }
  }

  if (EPI == 0) {
    const int nbase = n0 + wc * 64;        // aligned 64: one (which, head)
    const int which = nbase >> 10;
    const int h = (nbase & 1023) >> 6;
    const int b = m0 >> 11;                // whole block in one batch
    __bf16* base0 = (__bf16*)Cout + (size_t)which * (4u << 20);
    if (which < 2) {
      // Q / K with RoPE (Q also scaled)
      const float scale = (which == 0) ? QSCALE : 1.0f;
      __bf16* dst = base0 + ((size_t)(b * NH + h)) * SEQ * DKH;
      #pragma unroll
      for (int mf = 0; mf < 4; ++mf) {
        #pragma unroll
        for (int j = 0; j < 4; ++j) {
          int s = (m0 & (SEQ - 1)) + wr * 64 + mf * 16 + fq * 4 + j;
          #pragma unroll
          for (int nf = 0; nf < 2; ++nf) {
            int i = nf * 16 + fr;
            f32x2 cs = ((const f32x2*)tab)[s * 32 + i];
            float a = acc[mf][nf][j], bb = acc[mf][nf + 2][j];
            dst[(size_t)s * DKH + i]      = (__bf16)((a * cs[0] - bb * cs[1]) * scale);
            dst[(size_t)s * DKH + i + 32] = (__bf16)((bb * cs[0] + a * cs[1]) * scale);
          }
        }
      }
    } else {
      // V transposed + key-permuted: Vt[bh][dk][pi(s)]
      __bf16* dst = base0 + ((size_t)(b * NH + h)) * DKH * SEQ;
      #pragma unroll
      for (int mf = 0; mf < 4; ++mf) {
        #pragma unroll
        for (int nf = 0; nf < 4; ++nf) {
          int dk = nf * 16 + fr;
          #pragma unroll
          for (int j = 0; j < 4; ++j) {
            int sp = (m0 & (SEQ - 1)) + wr * 64 + (mf >> 1) * 32 + fq * 8 + (mf & 1) * 4 + j;
            dst[(size_t)dk * SEQ + sp] = (__bf16)acc[mf][nf][j];
          }
        }
      }
    }
  } else {
    #pragma unroll
    for (int mf = 0; mf < 4; ++mf)
      #pragma unroll
      for (int nf = 0; nf < NFR; ++nf)
        #pragma unroll
        for (int j = 0; j < 4; ++j) {
          int m = m0 + wr * 64 + mf * 16 + fq * 4 + j;
          int n = n0 + wc * (BN / 2) + nf * 16 + fr;
          ((float*)Cout)[(size_t)m * N + n] = acc[mf][nf][j];
        }
  }
}

// ---------------- causal flash attention, KVBLK=128, 9-iter blocks --------
// 512 blocks (32 bh x 16 slots), 512 threads = 8 waves, 128-row q-tiles.
// XCD remap: 16 slots of each bh land on one XCD. KV staged 128 keys/iter
// (2-deep, one barrier/iter), consumed as two 64-key sub-steps.
// Causal split-K in 128-units:
//   slot 0..7  (A): own tile qa: kv128 0..qa, flush; help qb=15-qa: kv 9..15-qa.
//   slot 8..15 (B): tile qb=slot: kv128 0..8.
// l accumulated as a 5th PV column (P x ones_B -> C[q][0]); no VALU adds.
// Partials stored BF16 (halves split-K HBM traffic; error ~0.4% rel, well
// under tolerance). No device fences/atomics (round-17 lesson).
__launch_bounds__(512, 4)
__global__ void attn_causal(const __bf16* __restrict__ Qg, const __bf16* __restrict__ Kg,
                            const __bf16* __restrict__ Vtg, __bf16* __restrict__ Out,
                            __bf16* __restrict__ P0, __bf16* __restrict__ P1,
                            float* __restrict__ L0, float* __restrict__ L1) {
  __shared__ __bf16 Ks[2][128 * 64];    // [t][d] swizzled (32KB)
  __shared__ __bf16 Vts[2][64 * 128];   // [d][slot] swizzled (32KB)
  const int tid = threadIdx.x;
  const int lane = tid & 63;
  const int w = tid >> 6;
  const int fr = lane & 15, fq = lane >> 4;
  // XCD remap: raw%8 == XCD; contiguous 64 nlids (4 bh) per XCD
  const int r = blockIdx.x;
  const int nlid = (r & 7) * 64 + (r >> 3);
  const int bh = nlid >> 4;
  const int slot = nlid & 15;
  const bool isA = slot < 8;
  const int qa = slot;                          // valid when isA
  const int qb = isA ? (15 - slot) : slot;      // 8..15
  const int sw  = isA ? (qa + 1) : 99;          // phase-switch iteration
  const int off = isA ? (8 - qa) : 0;           // kvt = it<sw ? it : it+off
  const int nst = isA ? 8 : 9;                  // iters that stage/compute
  const int b = bh >> 4, h = bh & 15;
  const __bf16* Qh = Qg + (size_t)bh * SEQ * DKH;
  const __bf16* Kh = Kg + (size_t)bh * SEQ * DKH;
  const __bf16* Vth = Vtg + (size_t)bh * DKH * SEQ;

  int qrow_lo = (isA ? qa : qb) * 128 + w * 16;

  // staging geometry (per-thread invariant), 1024 chunks per tile, 2 passes
  const int ck0 = tid, ck1 = 512 + tid;
  const int kr0 = ck0 >> 3, kc0 = ((ck0 & 7) ^ (kr0 & 7)) * 8;
  const int kr1 = ck1 >> 3, kc1 = ((ck1 & 7) ^ (kr1 & 7)) * 8;
  const int vd0 = ck0 >> 4, vk0 = (((ck0 & 15) & 8) | (((ck0 & 15) ^ vd0) & 7)) * 8;
  const int vd1 = ck1 >> 4, vk1 = (((ck1 & 15) & 8) | (((ck1 & 15) ^ vd1) & 7)) * 8;

#define STAGE(buf, kvt) {                                                     \
    const int ts_ = (kvt) << 7;                                               \
    gload16(&Kh[(size_t)(ts_ + kr0) * DKH + kc0], &Ks[buf][(w * 64) * 8]);    \
    gload16(&Kh[(size_t)(ts_ + kr1) * DKH + kc1], &Ks[buf][(512 + w * 64) * 8]); \
    gload16(&Vth[(size_t)vd0 * SEQ + ts_ + vk0], &Vts[buf][(w * 64) * 8]);    \
    gload16(&Vth[(size_t)vd1 * SEQ + ts_ + vk1], &Vts[buf][(512 + w * 64) * 8]); }

  bf16x8 qf[2];
  #pragma unroll
  for (int kk = 0; kk < 2; ++kk)
    qf[kk] = *(const bf16x8*)&Qh[(size_t)(qrow_lo + fr) * DKH + kk * 32 + fq * 8];

  // ones B-fragment: B[k][0]=1 -> C[q][0] = sum_k P[q][k] = l
  bf16x8 vones;
  #pragma unroll
  for (int e = 0; e < 8; ++e) vones[e] = (fr == 0) ? (__bf16)1.0f : (__bf16)0.0f;

  f32x4 Oa[4] = {};
  f32x4 Oa5 = {};                       // l column

  // prologue: stage kv128 tile 0
  STAGE(0, 0);
  __syncthreads();

  for (int it = 0; it < 9; ++it) {
    const int cur = it & 1;
    if (it + 1 < nst) {
      const int nx = it + 1;
      const int kvn = (nx < sw) ? nx : nx + off;
      STAGE(cur ^ 1, kvn);
    }
    if (isA && it == sw) {
      // ---- flush band-A rows (complete): normalize, write to Ab ----
      float rl[4];
      #pragma unroll
      for (int j = 0; j < 4; ++j)
        rl[j] = 1.0f / __shfl(Oa5[j], fq << 4);
      #pragma unroll
      for (int nf = 0; nf < 4; ++nf)
        #pragma unroll
        for (int j = 0; j < 4; ++j) {
          int qr = qrow_lo + fq * 4 + j;
          Out[((size_t)(b * SEQ) + qr) * DM + h * DKH + nf * 16 + fr] =
              (__bf16)(Oa[nf][j] * rl[j]);
        }
      // ---- switch to help band B ----
      #pragma unroll
      for (int nf = 0; nf < 4; ++nf) Oa[nf] = (f32x4){0.f, 0.f, 0.f, 0.f};
      Oa5 = (f32x4){0.f, 0.f, 0.f, 0.f};
      qrow_lo = qb * 128 + w * 16;
      #pragma unroll
      for (int kk = 0; kk < 2; ++kk)
        qf[kk] = *(const bf16x8*)&Qh[(size_t)(qrow_lo + fr) * DKH + kk * 32 + fq * 8];
    }
    if (it < nst) {
      const int kvt = (it < sw) ? it : it + off;
      #pragma unroll
      for (int sub = 0; sub < 2; ++sub) {
        const int ts = (kvt << 7) + (sub << 6);
        if (ts > qrow_lo + 15) continue;
        // ---- QK^T swapped: sacc[nf] = K_frag x Q_frag ----
        f32x4 sacc[4] = {};
        __builtin_amdgcn_s_setprio(1);
        #pragma unroll
        for (int kk = 0; kk < 2; ++kk) {
          #pragma unroll
          for (int nf = 0; nf < 4; ++nf) {
            int krow = (sub << 6) + nf * 16 + fr;
            bf16x8 kf = *(const bf16x8*)&Ks[cur][krow * 64 + ((kk * 32 + fq * 8) ^ ((fr & 7) << 3))];
            sacc[nf] = __builtin_amdgcn_mfma_f32_16x16x32_bf16(kf, qf[kk], sacc[nf], 0, 0, 0);
          }
        }
        __builtin_amdgcn_s_setprio(0);
        // ---- P = exp2(s); mask only on diagonal sub-tiles ----
        const bool need_mask = (ts + 63 > qrow_lo);
        if (need_mask) {
          const int qr = qrow_lo + fr;
          #pragma unroll
          for (int nf = 0; nf < 4; ++nf) {
            #pragma unroll
            for (int j = 0; j < 4; ++j) {
              float v = sacc[nf][j];
              int tc = ts + nf * 16 + fq * 4 + j;
              if (tc > qr) v = -INFINITY;
              sacc[nf][j] = exp2f(v);
            }
          }
        } else {
          #pragma unroll
          for (int nf = 0; nf < 4; ++nf) {
            #pragma unroll
            for (int j = 0; j < 4; ++j)
              sacc[nf][j] = exp2f(sacc[nf][j]);
          }
        }
        // ---- pack P to PV A-fragments (pure register) ----
        bf16x8 pa[2];
        #pragma unroll
        for (int kk = 0; kk < 2; ++kk)
          #pragma unroll
          for (int e = 0; e < 8; ++e)
            pa[kk][e] = (__bf16)sacc[2 * kk + (e >> 2)][e & 3];
        // ---- PV (+ l column) ----
        __builtin_amdgcn_s_setprio(1);
        #pragma unroll
        for (int kk = 0; kk < 2; ++kk) {
          #pragma unroll
          for (int nf = 0; nf < 4; ++nf) {
            int d = nf * 16 + fr;
            bf16x8 vf = *(const bf16x8*)&Vts[cur][d * 128 + (sub << 6) +
                         (((kk * 4 + fq) ^ (fr & 7)) << 3)];
            Oa[nf] = __builtin_amdgcn_mfma_f32_16x16x32_bf16(pa[kk], vf, Oa[nf], 0, 0, 0);
          }
          Oa5 = __builtin_amdgcn_mfma_f32_16x16x32_bf16(pa[kk], vones, Oa5, 0, 0, 0);
        }
        __builtin_amdgcn_s_setprio(0);
      }
    }
    __syncthreads();
  }
#undef STAGE
  // ---- final: write PARTIAL (O bf16, l fp32) for band-B rows ----
  __bf16* P = isA ? P1 : P0;
  float* L = isA ? L1 : L0;
  const int rbase = ((bh << 3) + (qb - 8)) << 7;   // *128 rows
  if (fr == 0) {
    #pragma unroll
    for (int j = 0; j < 4; ++j)
      L[rbase + w * 16 + fq * 4 + j] = Oa5[j];
  }
  #pragma unroll
  for (int nf = 0; nf < 4; ++nf)
    #pragma unroll
    for (int j = 0; j < 4; ++j)
      P[(size_t)(rbase + w * 16 + fq * 4 + j) * 64 + nf * 16 + fr] = (__bf16)Oa[nf][j];
}

// ---------------- combine split-K partials -> Ab rows 1024..2047 ----------
__global__ void combine(const __bf16* __restrict__ P0, const __bf16* __restrict__ P1,
                        const float* __restrict__ L0, const float* __restrict__ L1,
                        __bf16* __restrict__ Ab) {
  int t = blockIdx.x * blockDim.x + threadIdx.x;   // 262144
  int rowid = t >> 3, d0 = (t & 7) * 8;
  int bh = rowid >> 10, rem = rowid & 1023;
  int tq = rem >> 7, r = rem & 127;
  float rl = 1.0f / (L0[rowid] + L1[rowid]);
  bf16x8 a = *(const bf16x8*)(P0 + (size_t)rowid * 64 + d0);
  bf16x8 c = *(const bf16x8*)(P1 + (size_t)rowid * 64 + d0);
  bf16x8 o;
  #pragma unroll
  for (int e = 0; e < 8; ++e)
    o[e] = (__bf16)(((float)a[e] + (float)c[e]) * rl);
  int s = (tq + 8) * 128 + r;
  int b = bh >> 4, h = bh & 15;
  *(bf16x8*)&Ab[((size_t)b * SEQ + s) * DM + h * DKH + d0] = o;
}

extern "C" void kernel_launch(void* const* d_in, const int* in_sizes, int n_in,
                              void* d_out, int out_size, void* d_ws, size_t ws_size,
                              hipStream_t stream) {
  const float* x  = (const float*)d_in[0];
  const float* Wq = (const float*)d_in[1];
  const float* Wk = (const float*)d_in[2];
  const float* Wv = (const float*)d_in[3];
  const float* Wo = (const float*)d_in[4];

  char* ws = (char*)d_ws;
  __bf16* xb  = (__bf16*)(ws);                       // 8 MB
  __bf16* wqb = (__bf16*)(ws + ( 8u << 20));         // Wq,Wk,Wv,Wo contiguous
  __bf16* wob = (__bf16*)(ws + (14u << 20));
  __bf16* Qb  = (__bf16*)(ws + (16u << 20));         // [BH][S][64]
  __bf16* Kb  = (__bf16*)(ws + (24u << 20));         // = Qb + 4M elems
  __bf16* Vtb = (__bf16*)(ws + (32u << 20));         // = Qb + 8M elems, [BH][64][S] permuted
  __bf16* Ab  = (__bf16*)(ws + (40u << 20));         // [B*S][1024]
  float*  tab = (float*)(ws + (48u << 20));          // [SEQ][32] float2 (512 KB)
  float*  L0  = (float*)(ws + (49u << 20));          // 32768 floats (128 KB)
  float*  L1  = (float*)(ws + (49u << 20) + (1u << 18));
  // split-K O-partials (bf16) live in d_out (16 MB scratch, overwritten later)
  __bf16* P0 = (__bf16*)d_out;                        // 2M bf16 = 4 MB
  __bf16* P1 = P0 + (32768 * 64);

  prep<<<dim3(4352), dim3(256), 0, stream>>>(x, Wq, Wk, Wv, Wo, xb, wqb, tab);

  // merged QKV projection with fused RoPE/scale/V-transpose-permute epilogue
  gemm_bt<0, 128><<<dim3(32, 24), dim3(256), 0, stream>>>(xb, wqb, Qb, BATCH * SEQ, 3 * DM, DM, tab);

  attn_causal<<<dim3(512), dim3(512), 0, stream>>>(Qb, Kb, Vtb, Ab, P0, P1, L0, L1);

  combine<<<dim3(1024), dim3(256), 0, stream>>>(P0, P1, L0, L1, Ab);

  gemm_bt<1, 64><<<dim3(32, 16), dim3(256), 0, stream>>>(Ab, wob, d_out, BATCH * SEQ, DM, DM, nullptr);
}

// Round 20
// 93.995 us; speedup vs baseline: 2.7850x; 1.0055x over previous
//
#include <hip/hip_runtime.h>
#include <hip/hip_bf16.h>

#define BATCH 2
#define SEQ 2048
#define DM 1024
#define NH 16
#define DKH 64

typedef __attribute__((ext_vector_type(8))) __bf16 bf16x8;
typedef __attribute__((ext_vector_type(4))) __bf16 bf16x4;
typedef __attribute__((ext_vector_type(4))) float f32x4;
typedef __attribute__((ext_vector_type(2))) float f32x2;
typedef __attribute__((ext_vector_type(8))) unsigned short ushort8;

__device__ __forceinline__ void gload16(const void* g, void* l) {
  __builtin_amdgcn_global_load_lds(
      (const __attribute__((address_space(1))) void*)g,
      (__attribute__((address_space(3))) void*)l, 16, 0, 0);
}

// ------ merged prep: x cast | weight casts | RoPE table, one launch -------
__global__ void prep(const float* __restrict__ x,
                     const float* __restrict__ w0, const float* __restrict__ w1,
                     const float* __restrict__ w2, const float* __restrict__ w3,
                     __bf16* __restrict__ xb, __bf16* __restrict__ wb,
                     float* __restrict__ tab) {
  const int bid = blockIdx.x, tid = threadIdx.x;
  if (bid < 2048) {                       // x: 4M elems, 512K chunks of 8
    int i = bid * 256 + tid;
    f32x4 a = ((const f32x4*)x)[2 * i], b = ((const f32x4*)x)[2 * i + 1];
    bf16x8 o;
    o[0]=(__bf16)a[0]; o[1]=(__bf16)a[1]; o[2]=(__bf16)a[2]; o[3]=(__bf16)a[3];
    o[4]=(__bf16)b[0]; o[5]=(__bf16)b[1]; o[6]=(__bf16)b[2]; o[7]=(__bf16)b[3];
    ((bf16x8*)xb)[i] = o;
  } else if (bid < 4096) {                // weights: 4 x 1M elems contiguous dst
    int i = (bid - 2048) * 256 + tid;     // [0, 512K)
    int wi = i >> 17;
    const float* src = (wi == 0) ? w0 : (wi == 1) ? w1 : (wi == 2) ? w2 : w3;
    int li = i & 131071;
    f32x4 a = ((const f32x4*)src)[2 * li], b = ((const f32x4*)src)[2 * li + 1];
    bf16x8 o;
    o[0]=(__bf16)a[0]; o[1]=(__bf16)a[1]; o[2]=(__bf16)a[2]; o[3]=(__bf16)a[3];
    o[4]=(__bf16)b[0]; o[5]=(__bf16)b[1]; o[6]=(__bf16)b[2]; o[7]=(__bf16)b[3];
    ((bf16x8*)wb)[i] = o;
  } else {                                // RoPE table: 65536 (s,i) entries
    int idx = (bid - 4096) * 256 + tid;
    int s = idx >> 5, ii = idx & 31;
    float theta = exp2f((float)ii * -0.41524101186092029f);  // 10000^(-i/32)
    float sn, c;
    sincosf((float)s * theta, &sn, &c);
    tab[2 * idx] = c;
    tab[2 * idx + 1] = sn;
  }
}

#define QSCALE 0.1803368801111137f   // 0.125 * log2(e)

// ---------------- GEMM: C[m][n] = sum_k A[m][k] * B[n][k] -----------------
// m97 structure: 128xBN tile, BK=64, single-buffered 32KB LDS, 3 blocks/CU.
// XCD-aware block swizzle (grid linear count divisible by 8; gridDim.x==32).
// EPI 0 (BN=128): QKV projection, N=3072. Q (RoPE*QSCALE), K (RoPE) ->
//        [BH][S][64]; V -> transposed + KEY-PERMUTED [BH][64][S].
// EPI 1 (BN=64): fp32 row-major M x N.
template<int EPI, int BN>
__launch_bounds__(256, 3)
__global__ void gemm_bt(const __bf16* __restrict__ A, const __bf16* __restrict__ B,
                        void* __restrict__ Cout, int M, int N, int K,
                        const float* __restrict__ tab) {
  __shared__ __bf16 As[128 * 64];
  __shared__ __bf16 Bs[BN * 64];
  const int tid = threadIdx.x;
  const int lane = tid & 63;
  const int w = tid >> 6;
  const int wr = w >> 1, wc = w & 1;     // wave tile 64 x BN/2
  const int fr = lane & 15, fq = lane >> 4;
  // XCD swizzle: hw assigns lid%8 -> XCD; give each XCD a contiguous range
  const int lid = blockIdx.y * gridDim.x + blockIdx.x;
  const int total = gridDim.x * gridDim.y;
  const int nlid = (lid >> 3) + (lid & 7) * (total >> 3);
  const int bx = nlid & 31;             // gridDim.x == 32 for both GEMMs
  const int by = nlid >> 5;
  const int m0 = bx * 128;
  const int n0 = by * BN;
  const int NFR = BN / 32;               // B frags per wave

  f32x4 acc[4][BN / 32] = {};
  const int NT = K >> 6;

  for (int kt = 0; kt < NT; ++kt) {
    const int k0 = kt << 6;
    __syncthreads();
    #pragma unroll
    for (int p = 0; p < 4; ++p) {        // A: 1024 chunks
      int c = p * 256 + tid;
      int row = c >> 3, cs = (c & 7) ^ (row & 7);
      gload16(&A[(size_t)(m0 + row) * K + k0 + cs * 8], &As[(p * 256 + w * 64) * 8]);
    }
    #pragma unroll
    for (int p = 0; p < BN / 32; ++p) {  // B: BN*8 chunks
      int c = p * 256 + tid;
      int row = c >> 3, cs = (c & 7) ^ (row & 7);
      gload16(&B[(size_t)(n0 + row) * K + k0 + cs * 8], &Bs[(p * 256 + w * 64) * 8]);
    }
    __syncthreads();
    #pragma unroll
    for (int kk = 0; kk < 2; ++kk) {
      bf16x8 af[4], bfr[BN / 32];
      #pragma unroll
      for (int mf = 0; mf < 4; ++mf) {
        int row = wr * 64 + mf * 16 + fr;
        af[mf] = *(const bf16x8*)&As[row * 64 + ((kk * 32 + fq * 8) ^ ((fr & 7) << 3))];
      }
      #pragma unroll
      for (int nf = 0; nf < NFR; ++nf) {
        int row = wc * (BN / 2) + nf * 16 + fr;
        bfr[nf] = *(const bf16x8*)&Bs[row * 64 + ((kk * 32 + fq * 8) ^ ((fr & 7) << 3))];
      }
      __builtin_amdgcn_s_setprio(1);
      #pragma unroll
      for (int mf = 0; mf < 4; ++mf)
        #pragma unroll
        for (int nf = 0; nf < NFR; ++nf)
          acc[mf][nf] = __builtin_amdgcn_mfma_f32_16x16x32_bf16(af[mf], bfr[nf], acc[mf][nf], 0, 0, 0);
      __builtin_amdgcn_s_setprio(0);
    }
  }

  if (EPI == 0) {
    const int nbase = n0 + wc * 64;        // aligned 64: one (which, head)
    const int which = nbase >> 10;
    const int h = (nbase & 1023) >> 6;
    const int b = m0 >> 11;                // whole block in one batch
    __bf16* base0 = (__bf16*)Cout + (size_t)which * (4u << 20);
    if (which < 2) {
      // Q / K with RoPE (Q also scaled)
      const float scale = (which == 0) ? QSCALE : 1.0f;
      __bf16* dst = base0 + ((size_t)(b * NH + h)) * SEQ * DKH;
      #pragma unroll
      for (int mf = 0; mf < 4; ++mf) {
        #pragma unroll
        for (int j = 0; j < 4; ++j) {
          int s = (m0 & (SEQ - 1)) + wr * 64 + mf * 16 + fq * 4 + j;
          #pragma unroll
          for (int nf = 0; nf < 2; ++nf) {
            int i = nf * 16 + fr;
            f32x2 cs = ((const f32x2*)tab)[s * 32 + i];
            float a = acc[mf][nf][j], bb = acc[mf][nf + 2][j];
            dst[(size_t)s * DKH + i]      = (__bf16)((a * cs[0] - bb * cs[1]) * scale);
            dst[(size_t)s * DKH + i + 32] = (__bf16)((bb * cs[0] + a * cs[1]) * scale);
          }
        }
      }
    } else {
      // V transposed + key-permuted: Vt[bh][dk][pi(s)]; 4 j's contiguous in
      // the permuted index -> one 8B store per (mf,nf)
      __bf16* dst = base0 + ((size_t)(b * NH + h)) * DKH * SEQ;
      #pragma unroll
      for (int mf = 0; mf < 4; ++mf) {
        int sp = (m0 & (SEQ - 1)) + wr * 64 + (mf >> 1) * 32 + fq * 8 + (mf & 1) * 4;
        #pragma unroll
        for (int nf = 0; nf < 4; ++nf) {
          int dk = nf * 16 + fr;
          bf16x4 v4;
          #pragma unroll
          for (int j = 0; j < 4; ++j) v4[j] = (__bf16)acc[mf][nf][j];
          *(bf16x4*)&dst[(size_t)dk * SEQ + sp] = v4;
        }
      }
    }
  } else {
    #pragma unroll
    for (int mf = 0; mf < 4; ++mf)
      #pragma unroll
      for (int nf = 0; nf < NFR; ++nf)
        #pragma unroll
        for (int j = 0; j < 4; ++j) {
          int m = m0 + wr * 64 + mf * 16 + fq * 4 + j;
          int n = n0 + wc * (BN / 2) + nf * 16 + fr;
          ((float*)Cout)[(size_t)m * N + n] = acc[mf][nf][j];
        }
  }
}

// ---------------- causal flash attention, KVBLK=128, 9-iter blocks --------
// 512 blocks (32 bh x 16 slots), 512 threads = 8 waves, 128-row q-tiles.
// XCD remap: 16 slots of each bh land on one XCD. KV staged 128 keys/iter
// (2-deep, one barrier/iter), consumed as two 64-key sub-steps.
// Causal split-K in 128-units:
//   slot 0..7  (A): own tile qa: kv128 0..qa, flush; help qb=15-qa: kv 9..15-qa.
//   slot 8..15 (B): tile qb=slot: kv128 0..8.
// l accumulated as a 5th PV column (P x ones_B -> C[q][0]); no VALU adds.
// Band-B Q prefetched at start for A-blocks (switch is register-only).
// Partials stored BF16. No device fences/atomics (round-17 lesson).
__launch_bounds__(512, 4)
__global__ void attn_causal(const __bf16* __restrict__ Qg, const __bf16* __restrict__ Kg,
                            const __bf16* __restrict__ Vtg, __bf16* __restrict__ Out,
                            __bf16* __restrict__ P0, __bf16* __restrict__ P1,
                            float* __restrict__ L0, float* __restrict__ L1) {
  __shared__ __bf16 Ks[2][128 * 64];    // [t][d] swizzled (32KB)
  __shared__ __bf16 Vts[2][64 * 128];   // [d][slot] swizzled (32KB)
  const int tid = threadIdx.x;
  const int lane = tid & 63;
  const int w = tid >> 6;
  const int fr = lane & 15, fq = lane >> 4;
  // XCD remap: raw%8 == XCD; contiguous 64 nlids (4 bh) per XCD
  const int r = blockIdx.x;
  const int nlid = (r & 7) * 64 + (r >> 3);
  const int bh = nlid >> 4;
  const int slot = nlid & 15;
  const bool isA = slot < 8;
  const int qa = slot;                          // valid when isA
  const int qb = isA ? (15 - slot) : slot;      // 8..15
  const int sw  = isA ? (qa + 1) : 99;          // phase-switch iteration
  const int off = isA ? (8 - qa) : 0;           // kvt = it<sw ? it : it+off
  const int nst = isA ? 8 : 9;                  // iters that stage/compute
  const int b = bh >> 4, h = bh & 15;
  const __bf16* Qh = Qg + (size_t)bh * SEQ * DKH;
  const __bf16* Kh = Kg + (size_t)bh * SEQ * DKH;
  const __bf16* Vth = Vtg + (size_t)bh * DKH * SEQ;

  int qrow_lo = (isA ? qa : qb) * 128 + w * 16;

  // staging geometry (per-thread invariant), 1024 chunks per tile, 2 passes
  const int ck0 = tid, ck1 = 512 + tid;
  const int kr0 = ck0 >> 3, kc0 = ((ck0 & 7) ^ (kr0 & 7)) * 8;
  const int kr1 = ck1 >> 3, kc1 = ((ck1 & 7) ^ (kr1 & 7)) * 8;
  const int vd0 = ck0 >> 4, vk0 = (((ck0 & 15) & 8) | (((ck0 & 15) ^ vd0) & 7)) * 8;
  const int vd1 = ck1 >> 4, vk1 = (((ck1 & 15) & 8) | (((ck1 & 15) ^ vd1) & 7)) * 8;

#define STAGE(buf, kvt) {                                                     \
    const int ts_ = (kvt) << 7;                                               \
    gload16(&Kh[(size_t)(ts_ + kr0) * DKH + kc0], &Ks[buf][(w * 64) * 8]);    \
    gload16(&Kh[(size_t)(ts_ + kr1) * DKH + kc1], &Ks[buf][(512 + w * 64) * 8]); \
    gload16(&Vth[(size_t)vd0 * SEQ + ts_ + vk0], &Vts[buf][(w * 64) * 8]);    \
    gload16(&Vth[(size_t)vd1 * SEQ + ts_ + vk1], &Vts[buf][(512 + w * 64) * 8]); }

  bf16x8 qf[2], qfB[2];
  #pragma unroll
  for (int kk = 0; kk < 2; ++kk)
    qf[kk] = *(const bf16x8*)&Qh[(size_t)(qrow_lo + fr) * DKH + kk * 32 + fq * 8];
  if (isA) {
    #pragma unroll
    for (int kk = 0; kk < 2; ++kk)
      qfB[kk] = *(const bf16x8*)&Qh[(size_t)(qb * 128 + w * 16 + fr) * DKH + kk * 32 + fq * 8];
  }

  // ones B-fragment: B[k][0]=1 -> C[q][0] = sum_k P[q][k] = l
  bf16x8 vones;
  #pragma unroll
  for (int e = 0; e < 8; ++e) vones[e] = (fr == 0) ? (__bf16)1.0f : (__bf16)0.0f;

  f32x4 Oa[4] = {};
  f32x4 Oa5 = {};                       // l column

  // prologue: stage kv128 tile 0
  STAGE(0, 0);
  __syncthreads();

  for (int it = 0; it < 9; ++it) {
    const int cur = it & 1;
    if (it + 1 < nst) {
      const int nx = it + 1;
      const int kvn = (nx < sw) ? nx : nx + off;
      STAGE(cur ^ 1, kvn);
    }
    if (isA && it == sw) {
      // ---- flush band-A rows (complete): normalize, write to Ab ----
      float rl[4];
      #pragma unroll
      for (int j = 0; j < 4; ++j)
        rl[j] = 1.0f / __shfl(Oa5[j], fq << 4);
      #pragma unroll
      for (int nf = 0; nf < 4; ++nf)
        #pragma unroll
        for (int j = 0; j < 4; ++j) {
          int qr = qrow_lo + fq * 4 + j;
          Out[((size_t)(b * SEQ) + qr) * DM + h * DKH + nf * 16 + fr] =
              (__bf16)(Oa[nf][j] * rl[j]);
        }
      // ---- switch to help band B (register-only; Q was prefetched) ----
      #pragma unroll
      for (int nf = 0; nf < 4; ++nf) Oa[nf] = (f32x4){0.f, 0.f, 0.f, 0.f};
      Oa5 = (f32x4){0.f, 0.f, 0.f, 0.f};
      qrow_lo = qb * 128 + w * 16;
      #pragma unroll
      for (int kk = 0; kk < 2; ++kk) qf[kk] = qfB[kk];
    }
    if (it < nst) {
      const int kvt = (it < sw) ? it : it + off;
      #pragma unroll
      for (int sub = 0; sub < 2; ++sub) {
        const int ts = (kvt << 7) + (sub << 6);
        if (ts > qrow_lo + 15) continue;
        // ---- QK^T swapped: sacc[nf] = K_frag x Q_frag ----
        f32x4 sacc[4] = {};
        __builtin_amdgcn_s_setprio(1);
        #pragma unroll
        for (int kk = 0; kk < 2; ++kk) {
          #pragma unroll
          for (int nf = 0; nf < 4; ++nf) {
            int krow = (sub << 6) + nf * 16 + fr;
            bf16x8 kf = *(const bf16x8*)&Ks[cur][krow * 64 + ((kk * 32 + fq * 8) ^ ((fr & 7) << 3))];
            sacc[nf] = __builtin_amdgcn_mfma_f32_16x16x32_bf16(kf, qf[kk], sacc[nf], 0, 0, 0);
          }
        }
        __builtin_amdgcn_s_setprio(0);
        // ---- P = exp2(s); mask only on diagonal sub-tiles ----
        const bool need_mask = (ts + 63 > qrow_lo);
        if (need_mask) {
          const int qr = qrow_lo + fr;
          #pragma unroll
          for (int nf = 0; nf < 4; ++nf) {
            #pragma unroll
            for (int j = 0; j < 4; ++j) {
              float v = sacc[nf][j];
              int tc = ts + nf * 16 + fq * 4 + j;
              if (tc > qr) v = -INFINITY;
              sacc[nf][j] = exp2f(v);
            }
          }
        } else {
          #pragma unroll
          for (int nf = 0; nf < 4; ++nf) {
            #pragma unroll
            for (int j = 0; j < 4; ++j)
              sacc[nf][j] = exp2f(sacc[nf][j]);
          }
        }
        // ---- pack P to PV A-fragments (pure register) ----
        bf16x8 pa[2];
        #pragma unroll
        for (int kk = 0; kk < 2; ++kk)
          #pragma unroll
          for (int e = 0; e < 8; ++e)
            pa[kk][e] = (__bf16)sacc[2 * kk + (e >> 2)][e & 3];
        // ---- PV (+ l column) ----
        __builtin_amdgcn_s_setprio(1);
        #pragma unroll
        for (int kk = 0; kk < 2; ++kk) {
          #pragma unroll
          for (int nf = 0; nf < 4; ++nf) {
            int d = nf * 16 + fr;
            bf16x8 vf = *(const bf16x8*)&Vts[cur][d * 128 + (sub << 6) +
                         (((kk * 4 + fq) ^ (fr & 7)) << 3)];
            Oa[nf] = __builtin_amdgcn_mfma_f32_16x16x32_bf16(pa[kk], vf, Oa[nf], 0, 0, 0);
          }
          Oa5 = __builtin_amdgcn_mfma_f32_16x16x32_bf16(pa[kk], vones, Oa5, 0, 0, 0);
        }
        __builtin_amdgcn_s_setprio(0);
      }
    }
    __syncthreads();
  }
#undef STAGE
  // ---- final: write PARTIAL (O bf16, l fp32) for band-B rows ----
  __bf16* P = isA ? P1 : P0;
  float* L = isA ? L1 : L0;
  const int rbase = ((bh << 3) + (qb - 8)) << 7;   // *128 rows
  if (fr == 0) {
    #pragma unroll
    for (int j = 0; j < 4; ++j)
      L[rbase + w * 16 + fq * 4 + j] = Oa5[j];
  }
  #pragma unroll
  for (int nf = 0; nf < 4; ++nf)
    #pragma unroll
    for (int j = 0; j < 4; ++j)
      P[(size_t)(rbase + w * 16 + fq * 4 + j) * 64 + nf * 16 + fr] = (__bf16)Oa[nf][j];
}

// ---------------- combine split-K partials -> Ab rows 1024..2047 ----------
__global__ void combine(const __bf16* __restrict__ P0, const __bf16* __restrict__ P1,
                        const float* __restrict__ L0, const float* __restrict__ L1,
                        __bf16* __restrict__ Ab) {
  int t = blockIdx.x * blockDim.x + threadIdx.x;   // 262144
  int rowid = t >> 3, d0 = (t & 7) * 8;
  int bh = rowid >> 10, rem = rowid & 1023;
  int tq = rem >> 7, r = rem & 127;
  float rl = 1.0f / (L0[rowid] + L1[rowid]);
  bf16x8 a = *(const bf16x8*)(P0 + (size_t)rowid * 64 + d0);
  bf16x8 c = *(const bf16x8*)(P1 + (size_t)rowid * 64 + d0);
  bf16x8 o;
  #pragma unroll
  for (int e = 0; e < 8; ++e)
    o[e] = (__bf16)(((float)a[e] + (float)c[e]) * rl);
  int s = (tq + 8) * 128 + r;
  int b = bh >> 4, h = bh & 15;
  *(bf16x8*)&Ab[((size_t)b * SEQ + s) * DM + h * DKH + d0] = o;
}

extern "C" void kernel_launch(void* const* d_in, const int* in_sizes, int n_in,
                              void* d_out, int out_size, void* d_ws, size_t ws_size,
                              hipStream_t stream) {
  const float* x  = (const float*)d_in[0];
  const float* Wq = (const float*)d_in[1];
  const float* Wk = (const float*)d_in[2];
  const float* Wv = (const float*)d_in[3];
  const float* Wo = (const float*)d_in[4];

  char* ws = (char*)d_ws;
  __bf16* xb  = (__bf16*)(ws);                       // 8 MB
  __bf16* wqb = (__bf16*)(ws + ( 8u << 20));         // Wq,Wk,Wv,Wo contiguous
  __bf16* wob = (__bf16*)(ws + (14u << 20));
  __bf16* Qb  = (__bf16*)(ws + (16u << 20));         // [BH][S][64]
  __bf16* Kb  = (__bf16*)(ws + (24u << 20));         // = Qb + 4M elems
  __bf16* Vtb = (__bf16*)(ws + (32u << 20));         // = Qb + 8M elems, [BH][64][S] permuted
  __bf16* Ab  = (__bf16*)(ws + (40u << 20));         // [B*S][1024]
  float*  tab = (float*)(ws + (48u << 20));          // [SEQ][32] float2 (512 KB)
  float*  L0  = (float*)(ws + (49u << 20));          // 32768 floats (128 KB)
  float*  L1  = (float*)(ws + (49u << 20) + (1u << 18));
  // split-K O-partials (bf16) live in d_out (16 MB scratch, overwritten later)
  __bf16* P0 = (__bf16*)d_out;                        // 2M bf16 = 4 MB
  __bf16* P1 = P0 + (32768 * 64);

  prep<<<dim3(4352), dim3(256), 0, stream>>>(x, Wq, Wk, Wv, Wo, xb, wqb, tab);

  // merged QKV projection with fused RoPE/scale/V-transpose-permute epilogue
  gemm_bt<0, 128><<<dim3(32, 24), dim3(256), 0, stream>>>(xb, wqb, Qb, BATCH * SEQ, 3 * DM, DM, tab);

  attn_causal<<<dim3(512), dim3(512), 0, stream>>>(Qb, Kb, Vtb, Ab, P0, P1, L0, L1);

  combine<<<dim3(1024), dim3(256), 0, stream>>>(P0, P1, L0, L1, Ab);

  gemm_bt<1, 64><<<dim3(32, 16), dim3(256), 0, stream>>>(Ab, wob, d_out, BATCH * SEQ, DM, DM, nullptr);
}